// Round 9
// baseline (847.216 us; speedup 1.0000x reference)
//
#include <hip/hip_runtime.h>
#include <cstdint>

// ---------------------------------------------------------------------------
// DDPM + VAE query encoder, MI355X round 9: MFMA ddpm loop, weights in LDS.
// r8 post-mortem: VGPR=48 + FETCH=1.5GB -> the backend's register-target
// clamp sank the 32 weight-fragment VGPRs into the t-loop (refetch + resplit
// from L1 every step). Fix: stage the split bf16 hi/lo weight fragments in
// LDS (allocator can't touch it), transposed [n][k] stride-72 so each MFMA
// B-fragment is one contiguous ds_read_b128. Register demand ~50 -> under
// the clamp, nothing to sink. Arithmetic identical to the passing r8.
// ---------------------------------------------------------------------------

#define DEVI __device__ __forceinline__

typedef __attribute__((ext_vector_type(8))) short short8;
typedef __attribute__((ext_vector_type(4))) float f32x4;

DEVI uint32_t rotl32(uint32_t x, uint32_t r) { return (x << r) | (x >> (32u - r)); }

// JAX/Random123 threefry2x32, 20 rounds.
DEVI void threefry2x32(uint32_t k0, uint32_t k1, uint32_t x0, uint32_t x1,
                       uint32_t &o0, uint32_t &o1)
{
  const uint32_t ks2 = k0 ^ k1 ^ 0x1BD11BDAu;
  x0 += k0; x1 += k1;
#define TFR(r) { x0 += x1; x1 = rotl32(x1, r); x1 ^= x0; }
  TFR(13u) TFR(15u) TFR(26u) TFR(6u)   x0 += k1;  x1 += ks2 + 1u;
  TFR(17u) TFR(29u) TFR(16u) TFR(24u)  x0 += ks2; x1 += k0 + 2u;
  TFR(13u) TFR(15u) TFR(26u) TFR(6u)   x0 += k0;  x1 += k1 + 3u;
  TFR(17u) TFR(29u) TFR(16u) TFR(24u)  x0 += k1;  x1 += ks2 + 4u;
  TFR(13u) TFR(15u) TFR(26u) TFR(6u)   x0 += ks2; x1 += k0 + 5u;
#undef TFR
  o0 = x0; o1 = x1;
}

DEVI uint32_t jax_random_bits32(uint32_t k0, uint32_t k1, uint32_t j)
{
  uint32_t a, b;
  threefry2x32(k0, k1, 0u, j, a, b);
  return a ^ b;
}

// bits -> uniform [-1+eps, 1) -> sqrt(2)*erfinv(u) (XLA/Giles polynomial).
DEVI float jax_bits_to_normal(uint32_t bits)
{
  const float LO = -0.99999994f;
  float f = __uint_as_float((bits >> 9) | 0x3f800000u) - 1.0f;
  float u = fmaxf(LO, f * 2.0f + LO);
  float w = -__logf((1.0f - u) * (1.0f + u));
  float p;
  if (w < 5.0f) {
    w = w - 2.5f;
    p =              2.81022636e-08f;
    p = fmaf(p, w,   3.43273939e-07f);
    p = fmaf(p, w,  -3.5233877e-06f);
    p = fmaf(p, w,  -4.39150654e-06f);
    p = fmaf(p, w,   0.00021858087f);
    p = fmaf(p, w,  -0.00125372503f);
    p = fmaf(p, w,  -0.00417768164f);
    p = fmaf(p, w,   0.246640727f);
    p = fmaf(p, w,   1.50140941f);
  } else {
    w = sqrtf(w) - 3.0f;
    p =             -0.000200214257f;
    p = fmaf(p, w,   0.000100950558f);
    p = fmaf(p, w,   0.00134934322f);
    p = fmaf(p, w,  -0.00367342844f);
    p = fmaf(p, w,   0.00573950773f);
    p = fmaf(p, w,  -0.0076224613f);
    p = fmaf(p, w,   0.00943887047f);
    p = fmaf(p, w,   1.00167406f);
    p = fmaf(p, w,   2.83297682f);
  }
  return 1.41421356237f * (p * u);
}

// truncation-based fp32 -> bf16 hi + bf16 lo split (residual <= 2^-16 |x|)
DEVI short bf16_hi_trunc(float x) { return (short)(__float_as_uint(x) >> 16); }
DEVI float bf16_to_f32(short h)
{
  return __uint_as_float(((uint32_t)(unsigned short)h) << 16);
}
DEVI void split_bf16(float x, short &h, short &l)
{
  h = bf16_hi_trunc(x);
  float r = x - bf16_to_f32(h);
  l = bf16_hi_trunc(r);
}

// ---------------------------------------------------------------------------
// K_pool: 2048 blocks x 256 threads; wave per row, lane per dim.
__global__ __launch_bounds__(256)
void k_pool(const int* __restrict__ seq, const float* __restrict__ emb,
            float* __restrict__ pooled)
{
  const int lane = threadIdx.x & 63;
  const int r    = blockIdx.x * 4 + (threadIdx.x >> 6);
  const int* row = seq + r * 100;
  float s = 0.f;
  int cnt = 0;
  for (int l = 0; l < 100; ++l) {
    int id = row[l];
    cnt += (id != 0);
    s += emb[id * 64 + lane];
  }
  pooled[r * 64 + lane] = s / sqrtf((float)cnt);
}

// ---------------------------------------------------------------------------
// K_enc: 1024 blocks x 256 threads; 8 rows per block.
__global__ __launch_bounds__(256)
void k_enc(const float* __restrict__ pooled,
           const float* __restrict__ W1, const float* __restrict__ b1,
           const float* __restrict__ W2, const float* __restrict__ b2,
           const float* __restrict__ Wc, const float* __restrict__ bc,
           float* __restrict__ cproj)
{
  __shared__ float p_s[8][64];
  __shared__ float h_s[8][256];
  __shared__ float mu_s[8][64];
  const int tid = threadIdx.x;
  const int r0  = blockIdx.x * 8;

  for (int i = tid; i < 8 * 64; i += 256)
    p_s[i >> 6][i & 63] = pooled[r0 * 64 + i];
  __syncthreads();

  float hacc[8];
#pragma unroll
  for (int r = 0; r < 8; ++r) hacc[r] = b1[tid];
  for (int k = 0; k < 64; ++k) {
    float w = W1[k * 256 + tid];
#pragma unroll
    for (int r = 0; r < 8; ++r) hacc[r] = fmaf(p_s[r][k], w, hacc[r]);
  }
#pragma unroll
  for (int r = 0; r < 8; ++r) h_s[r][tid] = fmaxf(hacc[r], 0.f);
  __syncthreads();

#pragma unroll
  for (int pass = 0; pass < 2; ++pass) {
    int r = pass * 4 + (tid >> 6);
    int j = tid & 63;
    float acc = b2[j];
    for (int k = 0; k < 256; ++k)
      acc = fmaf(h_s[r][k], W2[k * 128 + j], acc);
    mu_s[r][j] = acc;
  }
  __syncthreads();

#pragma unroll
  for (int pass = 0; pass < 2; ++pass) {
    int r = pass * 4 + (tid >> 6);
    int j = tid & 63;
    float acc = bc[j];
    for (int k = 0; k < 64; ++k)
      acc = fmaf(mu_s[r][k], Wc[k * 64 + j], acc);
    cproj[(r0 + r) * 64 + j] = acc;
  }
}

// ---------------------------------------------------------------------------
// K_sched: single thread; layout sched[t*8 + {0:sr,1:srm1,2:c1,3:c2,4:sg}]
__global__ void k_sched(float* __restrict__ sched)
{
  if (threadIdx.x != 0 || blockIdx.x != 0) return;
  const float start = (float)(5.0 * 1e-4);
  const float stop  = (float)(5.0 * 0.02);
  const float delta = stop - start;
  float prod = 1.f;
  for (int i = 0; i < 200; ++i) {
    float beta  = start + ((float)i * delta) / 199.0f;
    float alpha = 1.0f - beta;
    float acp_prev = prod;
    prod = prod * alpha;
    float acp = prod;
    float om  = 1.0f - acp;
    sched[i * 8 + 0] = sqrtf(1.0f / acp);
    sched[i * 8 + 1] = sqrtf(1.0f / acp - 1.0f);
    sched[i * 8 + 2] = beta * sqrtf(acp_prev) / om;
    sched[i * 8 + 3] = (1.0f - acp_prev) * sqrtf(alpha) / om;
    float pv = beta * (1.0f - acp_prev) / om;
    sched[i * 8 + 4] = (i > 0) ? sqrtf(pv) : 0.0f;
  }
}

// ---------------------------------------------------------------------------
// K_tproj: 200 blocks x 64 threads; tpb[t][d] = temb(t)@W_t + b_t + b_in
__global__ __launch_bounds__(64)
void k_tproj(const float* __restrict__ Wt, const float* __restrict__ bt,
             const float* __restrict__ bin, float* __restrict__ tpb)
{
  __shared__ float temb[64];
  const int t = blockIdx.x;
  const int d = threadIdx.x;
  const float lg = logf(10000.0f);
  {
    int i = d & 31;
    float fr  = expf((-lg * (float)i) / 32.0f);
    float ang = (float)t * fr;
    temb[d] = (d < 32) ? cosf(ang) : sinf(ang);
  }
  __syncthreads();
  float acc = bt[d] + bin[d];
  for (int k = 0; k < 64; ++k)
    acc = fmaf(temb[k], Wt[k * 64 + d], acc);
  tpb[t * 64 + d] = acc;
}

// ---------------------------------------------------------------------------
// K_ddpm: 512 blocks x 256 threads (4 waves). Block owns 16 rows.
// Wave w computes N-tile cols [16w,16w+16) of both GEMVs via MFMA.
// Weights live in LDS as split bf16 hi/lo, transposed [n][k], stride 72.
#define LDSTRIDE 72   // shorts per row: 144 B, 16B-aligned, 2-way conflicts only

__global__ __launch_bounds__(256)
void k_ddpm(const float* __restrict__ Win, const float* __restrict__ Wout,
            const float* __restrict__ bout,
            const float* __restrict__ cproj, const float* __restrict__ tpb,
            const float* __restrict__ sched, float* __restrict__ out)
{
  __shared__ short Xh[16 * LDSTRIDE], Xl[16 * LDSTRIDE];
  __shared__ short Hh[16 * LDSTRIDE], Hl[16 * LDSTRIDE];
  __shared__ short WiHs[64 * LDSTRIDE], WiLs[64 * LDSTRIDE];
  __shared__ short WoHs[64 * LDSTRIDE], WoLs[64 * LDSTRIDE];

  const int tid  = threadIdx.x;
  const int lane = tid & 63;
  const int wv   = tid >> 6;             // 0..3 : N-tile
  const int nn   = lane & 15;
  const int quad = lane >> 4;
  const int dim  = wv * 16 + nn;         // global hidden/output dim
  const int rowq = quad * 4;             // rows rowq..rowq+3 in C-layout
  const int r0g  = blockIdx.x * 16;      // block's first batch row
  const int arow = lane & 15;            // A-fragment row (m)

  // ---- stage split weights into LDS, transposed [n][k] (one time)
  for (int idx = tid; idx < 4096; idx += 256) {
    int k = idx >> 6, n = idx & 63;
    short h, l;
    split_bf16(Win[idx], h, l);
    WiHs[n * LDSTRIDE + k] = h; WiLs[n * LDSTRIDE + k] = l;
    split_bf16(Wout[idx], h, l);
    WoHs[n * LDSTRIDE + k] = h; WoLs[n * LDSTRIDE + k] = l;
  }

  const float bo = bout[dim];
  float cp[4];
  uint32_t jj[4];
#pragma unroll
  for (int i = 0; i < 4; ++i) {
    cp[i] = cproj[(r0g + rowq + i) * 64 + dim];
    jj[i] = (uint32_t)((r0g + rowq + i) * 64 + dim);
  }

  // ---- x_init = normal(key(1)=[0,1]) at owned positions
  float xo[4];
#pragma unroll
  for (int i = 0; i < 4; ++i)
    xo[i] = jax_bits_to_normal(jax_random_bits32(0u, 1u, jj[i]));
#pragma unroll
  for (int i = 0; i < 4; ++i) {
    short h, l;
    split_bf16(xo[i], h, l);
    Xh[(rowq + i) * LDSTRIDE + dim] = h;
    Xl[(rowq + i) * LDSTRIDE + dim] = l;
  }
  __syncthreads();

#pragma unroll 1
  for (int t = 199; t >= 0; --t) {
    uint32_t fk0, fk1;
    threefry2x32(0u, 2u, 0u, (uint32_t)t, fk0, fk1);     // wave-uniform

    const float tp = tpb[t * 64 + dim];

    // ---- in-GEMV: A = X(16x64) @ Win(64x64), this wave's 16-col tile
    f32x4 acc;
#pragma unroll
    for (int i = 0; i < 4; ++i) acc[i] = tp + cp[i];
#pragma unroll
    for (int c = 0; c < 2; ++c) {
      short8 ah = *(const short8*)&Xh[arow * LDSTRIDE + c * 32 + quad * 8];
      short8 al = *(const short8*)&Xl[arow * LDSTRIDE + c * 32 + quad * 8];
      short8 bh = *(const short8*)&WiHs[dim * LDSTRIDE + c * 32 + quad * 8];
      short8 bl = *(const short8*)&WiLs[dim * LDSTRIDE + c * 32 + quad * 8];
      acc = __builtin_amdgcn_mfma_f32_16x16x32_bf16(al, bh, acc, 0, 0, 0);
      acc = __builtin_amdgcn_mfma_f32_16x16x32_bf16(ah, bl, acc, 0, 0, 0);
      acc = __builtin_amdgcn_mfma_f32_16x16x32_bf16(ah, bh, acc, 0, 0, 0);
    }

    // ---- silu, restage H
#pragma unroll
    for (int i = 0; i < 4; ++i) {
      float a = acc[i];
      float h = a * __builtin_amdgcn_rcpf(1.0f + __expf(-a));
      short hh, hl;
      split_bf16(h, hh, hl);
      Hh[(rowq + i) * LDSTRIDE + dim] = hh;
      Hl[(rowq + i) * LDSTRIDE + dim] = hl;
    }
    __syncthreads();                                      // B2

    // ---- out-GEMV: eps = H @ Wout + bout
    f32x4 eac;
#pragma unroll
    for (int i = 0; i < 4; ++i) eac[i] = bo;
#pragma unroll
    for (int c = 0; c < 2; ++c) {
      short8 ah = *(const short8*)&Hh[arow * LDSTRIDE + c * 32 + quad * 8];
      short8 al = *(const short8*)&Hl[arow * LDSTRIDE + c * 32 + quad * 8];
      short8 bh = *(const short8*)&WoHs[dim * LDSTRIDE + c * 32 + quad * 8];
      short8 bl = *(const short8*)&WoLs[dim * LDSTRIDE + c * 32 + quad * 8];
      eac = __builtin_amdgcn_mfma_f32_16x16x32_bf16(al, bh, eac, 0, 0, 0);
      eac = __builtin_amdgcn_mfma_f32_16x16x32_bf16(ah, bl, eac, 0, 0, 0);
      eac = __builtin_amdgcn_mfma_f32_16x16x32_bf16(ah, bh, eac, 0, 0, 0);
    }

    const float sr   = sched[t * 8 + 0];
    const float srm1 = sched[t * 8 + 1];
    const float c1   = sched[t * 8 + 2];
    const float c2   = sched[t * 8 + 3];
    const float sg   = sched[t * 8 + 4];

    // ---- per-element update + RNG (eps in registers, C-layout)
#pragma unroll
    for (int i = 0; i < 4; ++i) {
      float x0c = fminf(1.f, fmaxf(-1.f, sr * xo[i] - srm1 * eac[i]));
      float n   = jax_bits_to_normal(jax_random_bits32(fk0, fk1, jj[i]));
      xo[i]     = c1 * x0c + c2 * xo[i] + sg * n;
    }

    // ---- restage X for next step
#pragma unroll
    for (int i = 0; i < 4; ++i) {
      short h, l;
      split_bf16(xo[i], h, l);
      Xh[(rowq + i) * LDSTRIDE + dim] = h;
      Xl[(rowq + i) * LDSTRIDE + dim] = l;
    }
    __syncthreads();                                      // B3
  }

  // ---- final store (owned positions)
#pragma unroll
  for (int i = 0; i < 4; ++i)
    out[(r0g + rowq + i) * 64 + dim] = xo[i];
}

// ---------------------------------------------------------------------------
extern "C" void kernel_launch(void* const* d_in, const int* in_sizes, int n_in,
                              void* d_out, int out_size, void* d_ws, size_t ws_size,
                              hipStream_t stream)
{
  const int*   seq  = (const int*)  d_in[0];
  const float* emb  = (const float*)d_in[1];
  const float* W1   = (const float*)d_in[2];
  const float* b1   = (const float*)d_in[3];
  const float* W2   = (const float*)d_in[4];
  const float* b2   = (const float*)d_in[5];
  const float* Win  = (const float*)d_in[6];
  const float* bin  = (const float*)d_in[7];
  const float* Wt   = (const float*)d_in[8];
  const float* bt   = (const float*)d_in[9];
  const float* Wc   = (const float*)d_in[10];
  const float* bc   = (const float*)d_in[11];
  const float* Wout = (const float*)d_in[12];
  const float* bout = (const float*)d_in[13];

  float* out   = (float*)d_out;
  float* ws    = (float*)d_ws;
  float* cproj = ws;                       // 524288 floats
  float* tpb   = ws + 524288;              // 12800 floats
  float* sched = ws + 524288 + 12800;      // 1600 floats (t*8 layout)
  float* pooled = out;                     // reuse d_out as scratch

  k_pool <<<2048, 256, 0, stream>>>(seq, emb, pooled);
  k_enc  <<<1024, 256, 0, stream>>>(pooled, W1, b1, W2, b2, Wc, bc, cproj);
  k_sched<<<1, 64, 0, stream>>>(sched);
  k_tproj<<<200, 64, 0, stream>>>(Wt, bt, bin, tpb);
  k_ddpm <<<512, 256, 0, stream>>>(Win, Wout, bout, cproj, tpb, sched, out);
}

// Round 10
// 696.437 us; speedup vs baseline: 1.2165x; 1.2165x over previous
//
#include <hip/hip_runtime.h>
#include <cstdint>

// ---------------------------------------------------------------------------
// DDPM + VAE query encoder, MI355X round 10.
// r9 post-mortem: loop is overlap-bound (2 waves/SIMD, serial threefry chains,
// redundant wave-uniform fold-key threefry, in-loop tpb latency), not
// issue-bound. Changes:
//  - 512 blocks x 512 threads (8 waves): K-split (kc=w>>2) across wave pairs,
//    partial sums via LDS pacc [dim][20] (b128-aligned) -> 4 waves/SIMD.
//  - fold keys fk_t precomputed in k_sched (sched slots 5,6).
//  - RNG split: kc0 owns C rows 0,1; kc1 computes rows 2,3 noise (state-
//    independent) at iter top, passes via nbuf; kc0 does update for all 4.
//  - tpb software-prefetched one step ahead.
// RNG bit-mapping identical to passing r2-r9.
// ---------------------------------------------------------------------------

#define DEVI __device__ __forceinline__

typedef __attribute__((ext_vector_type(8))) short short8;
typedef __attribute__((ext_vector_type(4))) float f32x4;

DEVI uint32_t rotl32(uint32_t x, uint32_t r) { return (x << r) | (x >> (32u - r)); }

DEVI void threefry2x32(uint32_t k0, uint32_t k1, uint32_t x0, uint32_t x1,
                       uint32_t &o0, uint32_t &o1)
{
  const uint32_t ks2 = k0 ^ k1 ^ 0x1BD11BDAu;
  x0 += k0; x1 += k1;
#define TFR(r) { x0 += x1; x1 = rotl32(x1, r); x1 ^= x0; }
  TFR(13u) TFR(15u) TFR(26u) TFR(6u)   x0 += k1;  x1 += ks2 + 1u;
  TFR(17u) TFR(29u) TFR(16u) TFR(24u)  x0 += ks2; x1 += k0 + 2u;
  TFR(13u) TFR(15u) TFR(26u) TFR(6u)   x0 += k0;  x1 += k1 + 3u;
  TFR(17u) TFR(29u) TFR(16u) TFR(24u)  x0 += k1;  x1 += ks2 + 4u;
  TFR(13u) TFR(15u) TFR(26u) TFR(6u)   x0 += ks2; x1 += k0 + 5u;
#undef TFR
  o0 = x0; o1 = x1;
}

DEVI uint32_t jax_random_bits32(uint32_t k0, uint32_t k1, uint32_t j)
{
  uint32_t a, b;
  threefry2x32(k0, k1, 0u, j, a, b);
  return a ^ b;
}

DEVI float jax_bits_to_normal(uint32_t bits)
{
  const float LO = -0.99999994f;
  float f = __uint_as_float((bits >> 9) | 0x3f800000u) - 1.0f;
  float u = fmaxf(LO, f * 2.0f + LO);
  float w = -__logf((1.0f - u) * (1.0f + u));
  float p;
  if (w < 5.0f) {
    w = w - 2.5f;
    p =              2.81022636e-08f;
    p = fmaf(p, w,   3.43273939e-07f);
    p = fmaf(p, w,  -3.5233877e-06f);
    p = fmaf(p, w,  -4.39150654e-06f);
    p = fmaf(p, w,   0.00021858087f);
    p = fmaf(p, w,  -0.00125372503f);
    p = fmaf(p, w,  -0.00417768164f);
    p = fmaf(p, w,   0.246640727f);
    p = fmaf(p, w,   1.50140941f);
  } else {
    w = sqrtf(w) - 3.0f;
    p =             -0.000200214257f;
    p = fmaf(p, w,   0.000100950558f);
    p = fmaf(p, w,   0.00134934322f);
    p = fmaf(p, w,  -0.00367342844f);
    p = fmaf(p, w,   0.00573950773f);
    p = fmaf(p, w,  -0.0076224613f);
    p = fmaf(p, w,   0.00943887047f);
    p = fmaf(p, w,   1.00167406f);
    p = fmaf(p, w,   2.83297682f);
  }
  return 1.41421356237f * (p * u);
}

DEVI short bf16_hi_trunc(float x) { return (short)(__float_as_uint(x) >> 16); }
DEVI float bf16_to_f32(short h)
{
  return __uint_as_float(((uint32_t)(unsigned short)h) << 16);
}
DEVI void split_bf16(float x, short &h, short &l)
{
  h = bf16_hi_trunc(x);
  float r = x - bf16_to_f32(h);
  l = bf16_hi_trunc(r);
}

// ---------------------------------------------------------------------------
__global__ __launch_bounds__(256)
void k_pool(const int* __restrict__ seq, const float* __restrict__ emb,
            float* __restrict__ pooled)
{
  const int lane = threadIdx.x & 63;
  const int r    = blockIdx.x * 4 + (threadIdx.x >> 6);
  const int* row = seq + r * 100;
  float s = 0.f;
  int cnt = 0;
  for (int l = 0; l < 100; ++l) {
    int id = row[l];
    cnt += (id != 0);
    s += emb[id * 64 + lane];
  }
  pooled[r * 64 + lane] = s / sqrtf((float)cnt);
}

// ---------------------------------------------------------------------------
__global__ __launch_bounds__(256)
void k_enc(const float* __restrict__ pooled,
           const float* __restrict__ W1, const float* __restrict__ b1,
           const float* __restrict__ W2, const float* __restrict__ b2,
           const float* __restrict__ Wc, const float* __restrict__ bc,
           float* __restrict__ cproj)
{
  __shared__ float p_s[8][64];
  __shared__ float h_s[8][256];
  __shared__ float mu_s[8][64];
  const int tid = threadIdx.x;
  const int r0  = blockIdx.x * 8;

  for (int i = tid; i < 8 * 64; i += 256)
    p_s[i >> 6][i & 63] = pooled[r0 * 64 + i];
  __syncthreads();

  float hacc[8];
#pragma unroll
  for (int r = 0; r < 8; ++r) hacc[r] = b1[tid];
  for (int k = 0; k < 64; ++k) {
    float w = W1[k * 256 + tid];
#pragma unroll
    for (int r = 0; r < 8; ++r) hacc[r] = fmaf(p_s[r][k], w, hacc[r]);
  }
#pragma unroll
  for (int r = 0; r < 8; ++r) h_s[r][tid] = fmaxf(hacc[r], 0.f);
  __syncthreads();

#pragma unroll
  for (int pass = 0; pass < 2; ++pass) {
    int r = pass * 4 + (tid >> 6);
    int j = tid & 63;
    float acc = b2[j];
    for (int k = 0; k < 256; ++k)
      acc = fmaf(h_s[r][k], W2[k * 128 + j], acc);
    mu_s[r][j] = acc;
  }
  __syncthreads();

#pragma unroll
  for (int pass = 0; pass < 2; ++pass) {
    int r = pass * 4 + (tid >> 6);
    int j = tid & 63;
    float acc = bc[j];
    for (int k = 0; k < 64; ++k)
      acc = fmaf(mu_s[r][k], Wc[k * 64 + j], acc);
    cproj[(r0 + r) * 64 + j] = acc;
  }
}

// ---------------------------------------------------------------------------
// sched[t*8 + {0:sr,1:srm1,2:c1,3:c2,4:sg,5:fk0(bits),6:fk1(bits)}]
__global__ void k_sched(float* __restrict__ sched)
{
  if (threadIdx.x != 0 || blockIdx.x != 0) return;
  uint32_t* su = (uint32_t*)sched;
  const float start = (float)(5.0 * 1e-4);
  const float stop  = (float)(5.0 * 0.02);
  const float delta = stop - start;
  float prod = 1.f;
  for (int i = 0; i < 200; ++i) {
    float beta  = start + ((float)i * delta) / 199.0f;
    float alpha = 1.0f - beta;
    float acp_prev = prod;
    prod = prod * alpha;
    float acp = prod;
    float om  = 1.0f - acp;
    sched[i * 8 + 0] = sqrtf(1.0f / acp);
    sched[i * 8 + 1] = sqrtf(1.0f / acp - 1.0f);
    sched[i * 8 + 2] = beta * sqrtf(acp_prev) / om;
    sched[i * 8 + 3] = (1.0f - acp_prev) * sqrtf(alpha) / om;
    float pv = beta * (1.0f - acp_prev) / om;
    sched[i * 8 + 4] = (i > 0) ? sqrtf(pv) : 0.0f;
    uint32_t fk0, fk1;
    threefry2x32(0u, 2u, 0u, (uint32_t)i, fk0, fk1);
    su[i * 8 + 5] = fk0;
    su[i * 8 + 6] = fk1;
  }
}

// ---------------------------------------------------------------------------
__global__ __launch_bounds__(64)
void k_tproj(const float* __restrict__ Wt, const float* __restrict__ bt,
             const float* __restrict__ bin, float* __restrict__ tpb)
{
  __shared__ float temb[64];
  const int t = blockIdx.x;
  const int d = threadIdx.x;
  const float lg = logf(10000.0f);
  {
    int i = d & 31;
    float fr  = expf((-lg * (float)i) / 32.0f);
    float ang = (float)t * fr;
    temb[d] = (d < 32) ? cosf(ang) : sinf(ang);
  }
  __syncthreads();
  float acc = bt[d] + bin[d];
  for (int k = 0; k < 64; ++k)
    acc = fmaf(temb[k], Wt[k * 64 + d], acc);
  tpb[t * 64 + d] = acc;
}

// ---------------------------------------------------------------------------
// K_ddpm: 512 blocks x 512 threads (8 waves). Block owns 16 rows.
// Wave w: nt=w&3 (cols 16nt..16nt+15), kc=w>>2 (k in [32kc,32kc+32)).
#define LDW   72   // short stride, X/H/weight rows (144B, 16B-aligned)
#define PACCW 20   // float stride, pacc per-dim row (80B, 16B-aligned)
#define NBW   10   // float stride, nbuf per-dim row

__global__ __launch_bounds__(512)
void k_ddpm(const float* __restrict__ Win, const float* __restrict__ Wout,
            const float* __restrict__ bout,
            const float* __restrict__ cproj, const float* __restrict__ tpb,
            const float* __restrict__ sched, float* __restrict__ out)
{
  __shared__ short WiHs[64 * LDW], WiLs[64 * LDW];
  __shared__ short WoHs[64 * LDW], WoLs[64 * LDW];
  __shared__ short Xh[16 * LDW], Xl[16 * LDW], Hh[16 * LDW], Hl[16 * LDW];
  __shared__ float pacc[2 * 64 * PACCW];
  __shared__ float nbuf[64 * NBW];

  const int tid  = threadIdx.x;
  const int lane = tid & 63;
  const int w    = tid >> 6;
  const int nt   = w & 3;
  const int kc   = w >> 2;
  const int nn   = lane & 15;
  const int quad = lane >> 4;
  const int dim  = nt * 16 + nn;
  const int arow = nn;
  const int r0g  = blockIdx.x * 16;
  const int kofs = kc * 32 + quad * 8;

  // ---- stage split weights, transposed [n][k]
  for (int idx = tid; idx < 4096; idx += 512) {
    int k = idx >> 6, n = idx & 63;
    short h, l;
    split_bf16(Win[idx], h, l);
    WiHs[n * LDW + k] = h; WiLs[n * LDW + k] = l;
    split_bf16(Wout[idx], h, l);
    WoHs[n * LDW + k] = h; WoLs[n * LDW + k] = l;
  }

  const float bo = bout[dim];
  const uint32_t j0 = (uint32_t)((r0g + quad * 4) * 64 + dim);
  const uint32_t j1 = j0 + 64, j2 = j0 + 128, j3 = j0 + 192;

  float cp0 = 0.f, cp1 = 0.f, cp2 = 0.f, cp3 = 0.f;
  float xo0 = 0.f, xo1 = 0.f, xo2 = 0.f, xo3 = 0.f;
  if (kc == 0) {
    cp0 = cproj[j0]; cp1 = cproj[j1]; cp2 = cproj[j2]; cp3 = cproj[j3];
    xo0 = jax_bits_to_normal(jax_random_bits32(0u, 1u, j0));
    xo1 = jax_bits_to_normal(jax_random_bits32(0u, 1u, j1));
    xo2 = jax_bits_to_normal(jax_random_bits32(0u, 1u, j2));
    xo3 = jax_bits_to_normal(jax_random_bits32(0u, 1u, j3));
    short h, l;
    split_bf16(xo0, h, l); Xh[(quad*4+0)*LDW + dim] = h; Xl[(quad*4+0)*LDW + dim] = l;
    split_bf16(xo1, h, l); Xh[(quad*4+1)*LDW + dim] = h; Xl[(quad*4+1)*LDW + dim] = l;
    split_bf16(xo2, h, l); Xh[(quad*4+2)*LDW + dim] = h; Xl[(quad*4+2)*LDW + dim] = l;
    split_bf16(xo3, h, l); Xh[(quad*4+3)*LDW + dim] = h; Xl[(quad*4+3)*LDW + dim] = l;
  }
  __syncthreads();

  float tp = (kc == 0) ? tpb[199 * 64 + dim] : 0.f;

#pragma unroll 1
  for (int t = 199; t >= 0; --t) {
    const float sr   = sched[t * 8 + 0];
    const float srm1 = sched[t * 8 + 1];
    const float c1   = sched[t * 8 + 2];
    const float c2   = sched[t * 8 + 3];
    const float sg   = sched[t * 8 + 4];
    const uint32_t fk0 = ((const uint32_t*)sched)[t * 8 + 5];
    const uint32_t fk1 = ((const uint32_t*)sched)[t * 8 + 6];

    // noise (state-independent): kc0 -> rows 0,1 ; kc1 -> rows 2,3
    const uint32_t naj = (kc == 0) ? j0 : j2;
    const uint32_t nbj = (kc == 0) ? j1 : j3;
    float na = jax_bits_to_normal(jax_random_bits32(fk0, fk1, naj));
    float nb = jax_bits_to_normal(jax_random_bits32(fk0, fk1, nbj));

    // ---- phase 1: in-GEMV partial over own K-chunk
    f32x4 acc;
    if (kc == 0) {
      acc[0] = tp + cp0; acc[1] = tp + cp1; acc[2] = tp + cp2; acc[3] = tp + cp3;
    } else {
      acc[0] = 0.f; acc[1] = 0.f; acc[2] = 0.f; acc[3] = 0.f;
    }
    {
      short8 ah = *(const short8*)&Xh[arow * LDW + kofs];
      short8 al = *(const short8*)&Xl[arow * LDW + kofs];
      short8 bh = *(const short8*)&WiHs[dim * LDW + kofs];
      short8 bl = *(const short8*)&WiLs[dim * LDW + kofs];
      acc = __builtin_amdgcn_mfma_f32_16x16x32_bf16(al, bh, acc, 0, 0, 0);
      acc = __builtin_amdgcn_mfma_f32_16x16x32_bf16(ah, bl, acc, 0, 0, 0);
      acc = __builtin_amdgcn_mfma_f32_16x16x32_bf16(ah, bh, acc, 0, 0, 0);
    }
    *(f32x4*)&pacc[(kc * 64 + dim) * PACCW + quad * 4] = acc;
    __syncthreads();                                    // B1

    // ---- phase 2: kc0 reduce+silu+stage H; kc1 publish noise
    if (kc == 0) {
      f32x4 p1 = *(const f32x4*)&pacc[(64 + dim) * PACCW + quad * 4];
      short h, l;
      float v;
      v = acc[0] + p1[0]; v = v * __builtin_amdgcn_rcpf(1.0f + __expf(-v));
      split_bf16(v, h, l); Hh[(quad*4+0)*LDW + dim] = h; Hl[(quad*4+0)*LDW + dim] = l;
      v = acc[1] + p1[1]; v = v * __builtin_amdgcn_rcpf(1.0f + __expf(-v));
      split_bf16(v, h, l); Hh[(quad*4+1)*LDW + dim] = h; Hl[(quad*4+1)*LDW + dim] = l;
      v = acc[2] + p1[2]; v = v * __builtin_amdgcn_rcpf(1.0f + __expf(-v));
      split_bf16(v, h, l); Hh[(quad*4+2)*LDW + dim] = h; Hl[(quad*4+2)*LDW + dim] = l;
      v = acc[3] + p1[3]; v = v * __builtin_amdgcn_rcpf(1.0f + __expf(-v));
      split_bf16(v, h, l); Hh[(quad*4+3)*LDW + dim] = h; Hl[(quad*4+3)*LDW + dim] = l;
    } else {
      *(float2*)&nbuf[dim * NBW + quad * 2] = make_float2(na, nb);
    }
    int tn = (t > 0) ? (t - 1) : 0;
    float tpn = (kc == 0) ? tpb[tn * 64 + dim] : 0.f;   // prefetch next tp
    __syncthreads();                                    // B2

    // ---- phase 3: out-GEMV partial
    f32x4 eac;
    if (kc == 0) { eac[0] = bo; eac[1] = bo; eac[2] = bo; eac[3] = bo; }
    else         { eac[0] = 0.f; eac[1] = 0.f; eac[2] = 0.f; eac[3] = 0.f; }
    {
      short8 ah = *(const short8*)&Hh[arow * LDW + kofs];
      short8 al = *(const short8*)&Hl[arow * LDW + kofs];
      short8 bh = *(const short8*)&WoHs[dim * LDW + kofs];
      short8 bl = *(const short8*)&WoLs[dim * LDW + kofs];
      eac = __builtin_amdgcn_mfma_f32_16x16x32_bf16(al, bh, eac, 0, 0, 0);
      eac = __builtin_amdgcn_mfma_f32_16x16x32_bf16(ah, bl, eac, 0, 0, 0);
      eac = __builtin_amdgcn_mfma_f32_16x16x32_bf16(ah, bh, eac, 0, 0, 0);
    }
    *(f32x4*)&pacc[(kc * 64 + dim) * PACCW + quad * 4] = eac;
    __syncthreads();                                    // B3

    // ---- phase 4: kc0 finalize eps, update all 4 rows, restage X
    if (kc == 0) {
      f32x4 q1 = *(const f32x4*)&pacc[(64 + dim) * PACCW + quad * 4];
      float2 n23 = *(const float2*)&nbuf[dim * NBW + quad * 2];
      float e0 = eac[0] + q1[0], e1 = eac[1] + q1[1];
      float e2 = eac[2] + q1[2], e3 = eac[3] + q1[3];
#define UPD(xo, e, n)                                                          \
      {                                                                        \
        float xc = fminf(1.f, fmaxf(-1.f, sr * (xo) - srm1 * (e)));            \
        (xo) = c1 * xc + c2 * (xo) + sg * (n);                                 \
      }
      UPD(xo0, e0, na) UPD(xo1, e1, nb) UPD(xo2, e2, n23.x) UPD(xo3, e3, n23.y)
#undef UPD
      short h, l;
      split_bf16(xo0, h, l); Xh[(quad*4+0)*LDW + dim] = h; Xl[(quad*4+0)*LDW + dim] = l;
      split_bf16(xo1, h, l); Xh[(quad*4+1)*LDW + dim] = h; Xl[(quad*4+1)*LDW + dim] = l;
      split_bf16(xo2, h, l); Xh[(quad*4+2)*LDW + dim] = h; Xl[(quad*4+2)*LDW + dim] = l;
      split_bf16(xo3, h, l); Xh[(quad*4+3)*LDW + dim] = h; Xl[(quad*4+3)*LDW + dim] = l;
      tp = tpn;
    }
    __syncthreads();                                    // B4
  }

  if (kc == 0) {
    out[j0] = xo0; out[j1] = xo1; out[j2] = xo2; out[j3] = xo3;
  }
}

// ---------------------------------------------------------------------------
extern "C" void kernel_launch(void* const* d_in, const int* in_sizes, int n_in,
                              void* d_out, int out_size, void* d_ws, size_t ws_size,
                              hipStream_t stream)
{
  const int*   seq  = (const int*)  d_in[0];
  const float* emb  = (const float*)d_in[1];
  const float* W1   = (const float*)d_in[2];
  const float* b1   = (const float*)d_in[3];
  const float* W2   = (const float*)d_in[4];
  const float* b2   = (const float*)d_in[5];
  const float* Win  = (const float*)d_in[6];
  const float* bin  = (const float*)d_in[7];
  const float* Wt   = (const float*)d_in[8];
  const float* bt   = (const float*)d_in[9];
  const float* Wc   = (const float*)d_in[10];
  const float* bc   = (const float*)d_in[11];
  const float* Wout = (const float*)d_in[12];
  const float* bout = (const float*)d_in[13];

  float* out   = (float*)d_out;
  float* ws    = (float*)d_ws;
  float* cproj = ws;                       // 524288 floats
  float* tpb   = ws + 524288;              // 12800 floats
  float* sched = ws + 524288 + 12800;      // 1600 floats (t*8 layout)
  float* pooled = out;                     // reuse d_out as scratch

  k_pool <<<2048, 256, 0, stream>>>(seq, emb, pooled);
  k_enc  <<<1024, 256, 0, stream>>>(pooled, W1, b1, W2, b2, Wc, bc, cproj);
  k_sched<<<1, 64, 0, stream>>>(sched);
  k_tproj<<<200, 64, 0, stream>>>(Wt, bt, bin, tpb);
  k_ddpm <<<512, 512, 0, stream>>>(Win, Wout, bout, cproj, tpb, sched, out);
}

// Round 11
// 622.467 us; speedup vs baseline: 1.3611x; 1.1188x over previous
//
#include <hip/hip_runtime.h>
#include <cstdint>

// ---------------------------------------------------------------------------
// DDPM + VAE query encoder, MI355X round 11.
// vs r10: (1) LDS diet to 53,760B (stride 68 for weights and X/H; b64-pair
// fragment loads) -> 3 blocks/CU = 24 waves/CU; (2) symmetric row ownership:
// wave kc owns C-rows {2kc, 2kc+1} end-to-end (bias init, silu, update,
// staging, RNG) -> no nbuf, no idle phases; (3) stride-68 kills the 4-way
// staging-write conflicts (quads -> disjoint bank octets); (4) k_sched merged
// into k_prep (one less launch). RNG bit-mapping identical to r2-r10.
// ---------------------------------------------------------------------------

#define DEVI __device__ __forceinline__

typedef __attribute__((ext_vector_type(8))) short short8;
typedef __attribute__((ext_vector_type(4))) float f32x4;

DEVI uint32_t rotl32(uint32_t x, uint32_t r) { return (x << r) | (x >> (32u - r)); }

DEVI void threefry2x32(uint32_t k0, uint32_t k1, uint32_t x0, uint32_t x1,
                       uint32_t &o0, uint32_t &o1)
{
  const uint32_t ks2 = k0 ^ k1 ^ 0x1BD11BDAu;
  x0 += k0; x1 += k1;
#define TFR(r) { x0 += x1; x1 = rotl32(x1, r); x1 ^= x0; }
  TFR(13u) TFR(15u) TFR(26u) TFR(6u)   x0 += k1;  x1 += ks2 + 1u;
  TFR(17u) TFR(29u) TFR(16u) TFR(24u)  x0 += ks2; x1 += k0 + 2u;
  TFR(13u) TFR(15u) TFR(26u) TFR(6u)   x0 += k0;  x1 += k1 + 3u;
  TFR(17u) TFR(29u) TFR(16u) TFR(24u)  x0 += k1;  x1 += ks2 + 4u;
  TFR(13u) TFR(15u) TFR(26u) TFR(6u)   x0 += ks2; x1 += k0 + 5u;
#undef TFR
  o0 = x0; o1 = x1;
}

DEVI uint32_t jax_random_bits32(uint32_t k0, uint32_t k1, uint32_t j)
{
  uint32_t a, b;
  threefry2x32(k0, k1, 0u, j, a, b);
  return a ^ b;
}

DEVI float jax_bits_to_normal(uint32_t bits)
{
  const float LO = -0.99999994f;
  float f = __uint_as_float((bits >> 9) | 0x3f800000u) - 1.0f;
  float u = fmaxf(LO, f * 2.0f + LO);
  float w = -__logf((1.0f - u) * (1.0f + u));
  float p;
  if (w < 5.0f) {
    w = w - 2.5f;
    p =              2.81022636e-08f;
    p = fmaf(p, w,   3.43273939e-07f);
    p = fmaf(p, w,  -3.5233877e-06f);
    p = fmaf(p, w,  -4.39150654e-06f);
    p = fmaf(p, w,   0.00021858087f);
    p = fmaf(p, w,  -0.00125372503f);
    p = fmaf(p, w,  -0.00417768164f);
    p = fmaf(p, w,   0.246640727f);
    p = fmaf(p, w,   1.50140941f);
  } else {
    w = sqrtf(w) - 3.0f;
    p =             -0.000200214257f;
    p = fmaf(p, w,   0.000100950558f);
    p = fmaf(p, w,   0.00134934322f);
    p = fmaf(p, w,  -0.00367342844f);
    p = fmaf(p, w,   0.00573950773f);
    p = fmaf(p, w,  -0.0076224613f);
    p = fmaf(p, w,   0.00943887047f);
    p = fmaf(p, w,   1.00167406f);
    p = fmaf(p, w,   2.83297682f);
  }
  return 1.41421356237f * (p * u);
}

DEVI short bf16_hi_trunc(float x) { return (short)(__float_as_uint(x) >> 16); }
DEVI float bf16_to_f32(short h)
{
  return __uint_as_float(((uint32_t)(unsigned short)h) << 16);
}
DEVI void split_bf16(float x, short &h, short &l)
{
  h = bf16_hi_trunc(x);
  float r = x - bf16_to_f32(h);
  l = bf16_hi_trunc(r);
}

// 8-short fragment from 8B-aligned LDS (stride-68 rows): two b64 reads.
DEVI short8 ld_frag(const short* p)
{
  union { int4 v; short8 s; } u;
  const int2* q = (const int2*)p;
  int2 a = q[0], b = q[1];
  u.v = make_int4(a.x, a.y, b.x, b.y);
  return u.s;
}

// ---------------------------------------------------------------------------
__global__ __launch_bounds__(256)
void k_pool(const int* __restrict__ seq, const float* __restrict__ emb,
            float* __restrict__ pooled)
{
  const int lane = threadIdx.x & 63;
  const int r    = blockIdx.x * 4 + (threadIdx.x >> 6);
  const int* row = seq + r * 100;
  float s = 0.f;
  int cnt = 0;
  for (int l = 0; l < 100; ++l) {
    int id = row[l];
    cnt += (id != 0);
    s += emb[id * 64 + lane];
  }
  pooled[r * 64 + lane] = s / sqrtf((float)cnt);
}

// ---------------------------------------------------------------------------
__global__ __launch_bounds__(256)
void k_enc(const float* __restrict__ pooled,
           const float* __restrict__ W1, const float* __restrict__ b1,
           const float* __restrict__ W2, const float* __restrict__ b2,
           const float* __restrict__ Wc, const float* __restrict__ bc,
           float* __restrict__ cproj)
{
  __shared__ float p_s[8][64];
  __shared__ float h_s[8][256];
  __shared__ float mu_s[8][64];
  const int tid = threadIdx.x;
  const int r0  = blockIdx.x * 8;

  for (int i = tid; i < 8 * 64; i += 256)
    p_s[i >> 6][i & 63] = pooled[r0 * 64 + i];
  __syncthreads();

  float hacc[8];
#pragma unroll
  for (int r = 0; r < 8; ++r) hacc[r] = b1[tid];
  for (int k = 0; k < 64; ++k) {
    float w = W1[k * 256 + tid];
#pragma unroll
    for (int r = 0; r < 8; ++r) hacc[r] = fmaf(p_s[r][k], w, hacc[r]);
  }
#pragma unroll
  for (int r = 0; r < 8; ++r) h_s[r][tid] = fmaxf(hacc[r], 0.f);
  __syncthreads();

#pragma unroll
  for (int pass = 0; pass < 2; ++pass) {
    int r = pass * 4 + (tid >> 6);
    int j = tid & 63;
    float acc = b2[j];
    for (int k = 0; k < 256; ++k)
      acc = fmaf(h_s[r][k], W2[k * 128 + j], acc);
    mu_s[r][j] = acc;
  }
  __syncthreads();

#pragma unroll
  for (int pass = 0; pass < 2; ++pass) {
    int r = pass * 4 + (tid >> 6);
    int j = tid & 63;
    float acc = bc[j];
    for (int k = 0; k < 64; ++k)
      acc = fmaf(mu_s[r][k], Wc[k * 64 + j], acc);
    cproj[(r0 + r) * 64 + j] = acc;
  }
}

// ---------------------------------------------------------------------------
// k_prep: 200 blocks x 64 threads. Block t computes sched[t*8+..] (serial
// prefix cumprod, identical fp sequence to the original k_sched) AND
// tpb[t][d] = temb(t)@W_t + b_t + b_in.
__global__ __launch_bounds__(64)
void k_prep(const float* __restrict__ Wt, const float* __restrict__ bt,
            const float* __restrict__ bin, float* __restrict__ tpb,
            float* __restrict__ sched)
{
  __shared__ float temb[64];
  const int t = blockIdx.x;
  const int d = threadIdx.x;
  const float lg = logf(10000.0f);
  {
    int i = d & 31;
    float fr  = expf((-lg * (float)i) / 32.0f);
    float ang = (float)t * fr;
    temb[d] = (d < 32) ? cosf(ang) : sinf(ang);
  }
  if (d == 0) {
    const float start = (float)(5.0 * 1e-4);
    const float stop  = (float)(5.0 * 0.02);
    const float delta = stop - start;
    float prod = 1.f, acp_prev = 1.f, beta = 0.f, alpha = 1.f;
    for (int i = 0; i <= t; ++i) {
      beta  = start + ((float)i * delta) / 199.0f;
      alpha = 1.0f - beta;
      acp_prev = prod;
      prod = prod * alpha;
    }
    float acp = prod;
    float om  = 1.0f - acp;
    sched[t * 8 + 0] = sqrtf(1.0f / acp);
    sched[t * 8 + 1] = sqrtf(1.0f / acp - 1.0f);
    sched[t * 8 + 2] = beta * sqrtf(acp_prev) / om;
    sched[t * 8 + 3] = (1.0f - acp_prev) * sqrtf(alpha) / om;
    float pv = beta * (1.0f - acp_prev) / om;
    sched[t * 8 + 4] = (t > 0) ? sqrtf(pv) : 0.0f;
    uint32_t fk0, fk1;
    threefry2x32(0u, 2u, 0u, (uint32_t)t, fk0, fk1);
    ((uint32_t*)sched)[t * 8 + 5] = fk0;
    ((uint32_t*)sched)[t * 8 + 6] = fk1;
  }
  __syncthreads();
  float acc = bt[d] + bin[d];
  for (int k = 0; k < 64; ++k)
    acc = fmaf(temb[k], Wt[k * 64 + d], acc);
  tpb[t * 64 + d] = acc;
}

// ---------------------------------------------------------------------------
// K_ddpm: 512 blocks x 512 threads (8 waves). Block owns 16 rows.
// Wave w: nt=w&3 (cols 16nt..16nt+15), kc=w>>2 (K-chunk [32kc,32kc+32)).
// Wave kc owns C-rows {quad*4+2kc, quad*4+2kc+1} end-to-end.
#define WLDW  68   // weight row stride (shorts): 136B, 8B-aligned, quads on
                   // disjoint bank octets
#define XLDW  68   // X/H row stride (shorts)
#define PACCW 20   // pacc row stride (floats): 80B, 16B-aligned

__global__ __launch_bounds__(512)
void k_ddpm(const float* __restrict__ Win, const float* __restrict__ Wout,
            const float* __restrict__ bout,
            const float* __restrict__ cproj, const float* __restrict__ tpb,
            const float* __restrict__ sched, float* __restrict__ out)
{
  __shared__ short WiHs[64 * WLDW], WiLs[64 * WLDW];
  __shared__ short WoHs[64 * WLDW], WoLs[64 * WLDW];
  __shared__ short Xh[16 * XLDW], Xl[16 * XLDW], Hh[16 * XLDW], Hl[16 * XLDW];
  __shared__ float pacc[2 * 64 * PACCW];
  // total: 4*64*68*2 + 4*16*68*2 + 2*64*20*4 = 34816+8704+10240 = 53760 B
  // -> 3 blocks/CU (3*53760 = 161280 <= 163840)

  const int tid  = threadIdx.x;
  const int lane = tid & 63;
  const int w    = tid >> 6;
  const int nt   = w & 3;
  const int kc   = w >> 2;
  const int nn   = lane & 15;
  const int quad = lane >> 4;
  const int dim  = nt * 16 + nn;
  const int arow = nn;
  const int r0g  = blockIdx.x * 16;
  const int kofs = kc * 32 + quad * 8;
  const int rA   = quad * 4 + 2 * kc;       // owned C-rows rA, rA+1

  // ---- stage split weights, transposed [n][k]
  for (int idx = tid; idx < 4096; idx += 512) {
    int k = idx >> 6, n = idx & 63;
    short h, l;
    split_bf16(Win[idx], h, l);
    WiHs[n * WLDW + k] = h; WiLs[n * WLDW + k] = l;
    split_bf16(Wout[idx], h, l);
    WoHs[n * WLDW + k] = h; WoLs[n * WLDW + k] = l;
  }

  const float bo = bout[dim];
  const uint32_t jA = (uint32_t)((r0g + rA) * 64 + dim);
  const uint32_t jB = jA + 64u;
  const float cpA = cproj[jA];
  const float cpB = cproj[jB];

  // ---- x_init at owned positions
  float xoA = jax_bits_to_normal(jax_random_bits32(0u, 1u, jA));
  float xoB = jax_bits_to_normal(jax_random_bits32(0u, 1u, jB));
  {
    short h, l;
    split_bf16(xoA, h, l); Xh[rA * XLDW + dim] = h; Xl[rA * XLDW + dim] = l;
    split_bf16(xoB, h, l); Xh[(rA+1) * XLDW + dim] = h; Xl[(rA+1) * XLDW + dim] = l;
  }
  __syncthreads();

  float tp = tpb[199 * 64 + dim];

#pragma unroll 1
  for (int t = 199; t >= 0; --t) {
    const float sr   = sched[t * 8 + 0];
    const float srm1 = sched[t * 8 + 1];
    const float c1   = sched[t * 8 + 2];
    const float c2   = sched[t * 8 + 3];
    const float sg   = sched[t * 8 + 4];
    const uint32_t fk0 = ((const uint32_t*)sched)[t * 8 + 5];
    const uint32_t fk1 = ((const uint32_t*)sched)[t * 8 + 6];

    // noise for owned rows (state-independent)
    float nA = jax_bits_to_normal(jax_random_bits32(fk0, fk1, jA));
    float nB = jax_bits_to_normal(jax_random_bits32(fk0, fk1, jB));

    // ---- phase 1: in-GEMV partial over own K-chunk (bias on owned rows)
    f32x4 acc;
    if (kc == 0) { acc[0] = tp + cpA; acc[1] = tp + cpB; acc[2] = 0.f; acc[3] = 0.f; }
    else         { acc[0] = 0.f; acc[1] = 0.f; acc[2] = tp + cpA; acc[3] = tp + cpB; }
    {
      short8 ah = ld_frag(&Xh[arow * XLDW + kofs]);
      short8 al = ld_frag(&Xl[arow * XLDW + kofs]);
      short8 bh = ld_frag(&WiHs[dim * WLDW + kofs]);
      short8 bl = ld_frag(&WiLs[dim * WLDW + kofs]);
      acc = __builtin_amdgcn_mfma_f32_16x16x32_bf16(al, bh, acc, 0, 0, 0);
      acc = __builtin_amdgcn_mfma_f32_16x16x32_bf16(ah, bl, acc, 0, 0, 0);
      acc = __builtin_amdgcn_mfma_f32_16x16x32_bf16(ah, bh, acc, 0, 0, 0);
    }
    *(f32x4*)&pacc[(kc * 64 + dim) * PACCW + quad * 4] = acc;
    __syncthreads();                                    // B1

    // ---- phase 2: finalize h for owned rows, silu, stage H
    {
      float vA, vB;
      if (kc == 0) {
        float2 o = *(const float2*)&pacc[(64 + dim) * PACCW + quad * 4];
        vA = acc[0] + o.x; vB = acc[1] + o.y;
      } else {
        float2 o = *(const float2*)&pacc[dim * PACCW + quad * 4 + 2];
        vA = acc[2] + o.x; vB = acc[3] + o.y;
      }
      vA = vA * __builtin_amdgcn_rcpf(1.0f + __expf(-vA));
      vB = vB * __builtin_amdgcn_rcpf(1.0f + __expf(-vB));
      short h, l;
      split_bf16(vA, h, l); Hh[rA * XLDW + dim] = h; Hl[rA * XLDW + dim] = l;
      split_bf16(vB, h, l); Hh[(rA+1) * XLDW + dim] = h; Hl[(rA+1) * XLDW + dim] = l;
    }
    int tn = (t > 0) ? (t - 1) : 0;
    float tpn = tpb[tn * 64 + dim];                     // prefetch next tp
    __syncthreads();                                    // B2

    // ---- phase 3: out-GEMV partial (bias on owned rows)
    f32x4 eac;
    if (kc == 0) { eac[0] = bo; eac[1] = bo; eac[2] = 0.f; eac[3] = 0.f; }
    else         { eac[0] = 0.f; eac[1] = 0.f; eac[2] = bo; eac[3] = bo; }
    {
      short8 ah = ld_frag(&Hh[arow * XLDW + kofs]);
      short8 al = ld_frag(&Hl[arow * XLDW + kofs]);
      short8 bh = ld_frag(&WoHs[dim * WLDW + kofs]);
      short8 bl = ld_frag(&WoLs[dim * WLDW + kofs]);
      eac = __builtin_amdgcn_mfma_f32_16x16x32_bf16(al, bh, eac, 0, 0, 0);
      eac = __builtin_amdgcn_mfma_f32_16x16x32_bf16(ah, bl, eac, 0, 0, 0);
      eac = __builtin_amdgcn_mfma_f32_16x16x32_bf16(ah, bh, eac, 0, 0, 0);
    }
    *(f32x4*)&pacc[(kc * 64 + dim) * PACCW + quad * 4] = eac;
    __syncthreads();                                    // B3

    // ---- phase 4: finalize eps for owned rows, update, restage X
    {
      float eA, eB;
      if (kc == 0) {
        float2 o = *(const float2*)&pacc[(64 + dim) * PACCW + quad * 4];
        eA = eac[0] + o.x; eB = eac[1] + o.y;
      } else {
        float2 o = *(const float2*)&pacc[dim * PACCW + quad * 4 + 2];
        eA = eac[2] + o.x; eB = eac[3] + o.y;
      }
      float xcA = fminf(1.f, fmaxf(-1.f, sr * xoA - srm1 * eA));
      float xcB = fminf(1.f, fmaxf(-1.f, sr * xoB - srm1 * eB));
      xoA = c1 * xcA + c2 * xoA + sg * nA;
      xoB = c1 * xcB + c2 * xoB + sg * nB;
      short h, l;
      split_bf16(xoA, h, l); Xh[rA * XLDW + dim] = h; Xl[rA * XLDW + dim] = l;
      split_bf16(xoB, h, l); Xh[(rA+1) * XLDW + dim] = h; Xl[(rA+1) * XLDW + dim] = l;
      tp = tpn;
    }
    __syncthreads();                                    // B4
  }

  out[jA] = xoA;
  out[jB] = xoB;
}

// ---------------------------------------------------------------------------
extern "C" void kernel_launch(void* const* d_in, const int* in_sizes, int n_in,
                              void* d_out, int out_size, void* d_ws, size_t ws_size,
                              hipStream_t stream)
{
  const int*   seq  = (const int*)  d_in[0];
  const float* emb  = (const float*)d_in[1];
  const float* W1   = (const float*)d_in[2];
  const float* b1   = (const float*)d_in[3];
  const float* W2   = (const float*)d_in[4];
  const float* b2   = (const float*)d_in[5];
  const float* Win  = (const float*)d_in[6];
  const float* bin  = (const float*)d_in[7];
  const float* Wt   = (const float*)d_in[8];
  const float* bt   = (const float*)d_in[9];
  const float* Wc   = (const float*)d_in[10];
  const float* bc   = (const float*)d_in[11];
  const float* Wout = (const float*)d_in[12];
  const float* bout = (const float*)d_in[13];

  float* out   = (float*)d_out;
  float* ws    = (float*)d_ws;
  float* cproj = ws;                       // 524288 floats
  float* tpb   = ws + 524288;              // 12800 floats
  float* sched = ws + 524288 + 12800;      // 1600 floats (t*8 layout)
  float* pooled = out;                     // reuse d_out as scratch

  k_pool <<<2048, 256, 0, stream>>>(seq, emb, pooled);
  k_enc  <<<1024, 256, 0, stream>>>(pooled, W1, b1, W2, b2, Wc, bc, cproj);
  k_prep <<<200, 64, 0, stream>>>(Wt, bt, bin, tpb, sched);
  k_ddpm <<<512, 512, 0, stream>>>(Win, Wout, bout, cproj, tpb, sched, out);
}

// Round 12
// 604.443 us; speedup vs baseline: 1.4016x; 1.0298x over previous
//
#include <hip/hip_runtime.h>
#include <cstdint>

// ---------------------------------------------------------------------------
// DDPM + VAE query encoder, MI355X round 12.
// r11 post-mortem: occupancy is GRID-limited (512 blocks x 8 waves = 16
// waves/CU = 4/SIMD); LDS dieting for 3 blocks/CU was moot. VGPR_Count=40
// means the backend remats addresses/constants in-loop chasing unreachable
// occupancy. Fixes vs r11:
//  (1) __launch_bounds__(512,4): honest 4-waves/EU target -> 128-VGPR budget.
//  (2) pacc exchange shrunk to float2 (only non-owned row partials), stride
//      10; LDS 53760 -> 48640 B; fewer LDS ops. Bit-identical arithmetic.
// ---------------------------------------------------------------------------

#define DEVI __device__ __forceinline__

typedef __attribute__((ext_vector_type(8))) short short8;
typedef __attribute__((ext_vector_type(4))) float f32x4;

DEVI uint32_t rotl32(uint32_t x, uint32_t r) { return (x << r) | (x >> (32u - r)); }

DEVI void threefry2x32(uint32_t k0, uint32_t k1, uint32_t x0, uint32_t x1,
                       uint32_t &o0, uint32_t &o1)
{
  const uint32_t ks2 = k0 ^ k1 ^ 0x1BD11BDAu;
  x0 += k0; x1 += k1;
#define TFR(r) { x0 += x1; x1 = rotl32(x1, r); x1 ^= x0; }
  TFR(13u) TFR(15u) TFR(26u) TFR(6u)   x0 += k1;  x1 += ks2 + 1u;
  TFR(17u) TFR(29u) TFR(16u) TFR(24u)  x0 += ks2; x1 += k0 + 2u;
  TFR(13u) TFR(15u) TFR(26u) TFR(6u)   x0 += k0;  x1 += k1 + 3u;
  TFR(17u) TFR(29u) TFR(16u) TFR(24u)  x0 += k1;  x1 += ks2 + 4u;
  TFR(13u) TFR(15u) TFR(26u) TFR(6u)   x0 += ks2; x1 += k0 + 5u;
#undef TFR
  o0 = x0; o1 = x1;
}

DEVI uint32_t jax_random_bits32(uint32_t k0, uint32_t k1, uint32_t j)
{
  uint32_t a, b;
  threefry2x32(k0, k1, 0u, j, a, b);
  return a ^ b;
}

DEVI float jax_bits_to_normal(uint32_t bits)
{
  const float LO = -0.99999994f;
  float f = __uint_as_float((bits >> 9) | 0x3f800000u) - 1.0f;
  float u = fmaxf(LO, f * 2.0f + LO);
  float w = -__logf((1.0f - u) * (1.0f + u));
  float p;
  if (w < 5.0f) {
    w = w - 2.5f;
    p =              2.81022636e-08f;
    p = fmaf(p, w,   3.43273939e-07f);
    p = fmaf(p, w,  -3.5233877e-06f);
    p = fmaf(p, w,  -4.39150654e-06f);
    p = fmaf(p, w,   0.00021858087f);
    p = fmaf(p, w,  -0.00125372503f);
    p = fmaf(p, w,  -0.00417768164f);
    p = fmaf(p, w,   0.246640727f);
    p = fmaf(p, w,   1.50140941f);
  } else {
    w = sqrtf(w) - 3.0f;
    p =             -0.000200214257f;
    p = fmaf(p, w,   0.000100950558f);
    p = fmaf(p, w,   0.00134934322f);
    p = fmaf(p, w,  -0.00367342844f);
    p = fmaf(p, w,   0.00573950773f);
    p = fmaf(p, w,  -0.0076224613f);
    p = fmaf(p, w,   0.00943887047f);
    p = fmaf(p, w,   1.00167406f);
    p = fmaf(p, w,   2.83297682f);
  }
  return 1.41421356237f * (p * u);
}

DEVI short bf16_hi_trunc(float x) { return (short)(__float_as_uint(x) >> 16); }
DEVI float bf16_to_f32(short h)
{
  return __uint_as_float(((uint32_t)(unsigned short)h) << 16);
}
DEVI void split_bf16(float x, short &h, short &l)
{
  h = bf16_hi_trunc(x);
  float r = x - bf16_to_f32(h);
  l = bf16_hi_trunc(r);
}

// 8-short fragment from 8B-aligned LDS (stride-68 rows): two b64 reads.
DEVI short8 ld_frag(const short* p)
{
  union { int4 v; short8 s; } u;
  const int2* q = (const int2*)p;
  int2 a = q[0], b = q[1];
  u.v = make_int4(a.x, a.y, b.x, b.y);
  return u.s;
}

// ---------------------------------------------------------------------------
__global__ __launch_bounds__(256)
void k_pool(const int* __restrict__ seq, const float* __restrict__ emb,
            float* __restrict__ pooled)
{
  const int lane = threadIdx.x & 63;
  const int r    = blockIdx.x * 4 + (threadIdx.x >> 6);
  const int* row = seq + r * 100;
  float s = 0.f;
  int cnt = 0;
  for (int l = 0; l < 100; ++l) {
    int id = row[l];
    cnt += (id != 0);
    s += emb[id * 64 + lane];
  }
  pooled[r * 64 + lane] = s / sqrtf((float)cnt);
}

// ---------------------------------------------------------------------------
__global__ __launch_bounds__(256)
void k_enc(const float* __restrict__ pooled,
           const float* __restrict__ W1, const float* __restrict__ b1,
           const float* __restrict__ W2, const float* __restrict__ b2,
           const float* __restrict__ Wc, const float* __restrict__ bc,
           float* __restrict__ cproj)
{
  __shared__ float p_s[8][64];
  __shared__ float h_s[8][256];
  __shared__ float mu_s[8][64];
  const int tid = threadIdx.x;
  const int r0  = blockIdx.x * 8;

  for (int i = tid; i < 8 * 64; i += 256)
    p_s[i >> 6][i & 63] = pooled[r0 * 64 + i];
  __syncthreads();

  float hacc[8];
#pragma unroll
  for (int r = 0; r < 8; ++r) hacc[r] = b1[tid];
  for (int k = 0; k < 64; ++k) {
    float w = W1[k * 256 + tid];
#pragma unroll
    for (int r = 0; r < 8; ++r) hacc[r] = fmaf(p_s[r][k], w, hacc[r]);
  }
#pragma unroll
  for (int r = 0; r < 8; ++r) h_s[r][tid] = fmaxf(hacc[r], 0.f);
  __syncthreads();

#pragma unroll
  for (int pass = 0; pass < 2; ++pass) {
    int r = pass * 4 + (tid >> 6);
    int j = tid & 63;
    float acc = b2[j];
    for (int k = 0; k < 256; ++k)
      acc = fmaf(h_s[r][k], W2[k * 128 + j], acc);
    mu_s[r][j] = acc;
  }
  __syncthreads();

#pragma unroll
  for (int pass = 0; pass < 2; ++pass) {
    int r = pass * 4 + (tid >> 6);
    int j = tid & 63;
    float acc = bc[j];
    for (int k = 0; k < 64; ++k)
      acc = fmaf(mu_s[r][k], Wc[k * 64 + j], acc);
    cproj[(r0 + r) * 64 + j] = acc;
  }
}

// ---------------------------------------------------------------------------
// k_prep: 200 blocks x 64 threads. Block t computes sched[t*8+..] AND
// tpb[t][d] = temb(t)@W_t + b_t + b_in.
__global__ __launch_bounds__(64)
void k_prep(const float* __restrict__ Wt, const float* __restrict__ bt,
            const float* __restrict__ bin, float* __restrict__ tpb,
            float* __restrict__ sched)
{
  __shared__ float temb[64];
  const int t = blockIdx.x;
  const int d = threadIdx.x;
  const float lg = logf(10000.0f);
  {
    int i = d & 31;
    float fr  = expf((-lg * (float)i) / 32.0f);
    float ang = (float)t * fr;
    temb[d] = (d < 32) ? cosf(ang) : sinf(ang);
  }
  if (d == 0) {
    const float start = (float)(5.0 * 1e-4);
    const float stop  = (float)(5.0 * 0.02);
    const float delta = stop - start;
    float prod = 1.f, acp_prev = 1.f, beta = 0.f, alpha = 1.f;
    for (int i = 0; i <= t; ++i) {
      beta  = start + ((float)i * delta) / 199.0f;
      alpha = 1.0f - beta;
      acp_prev = prod;
      prod = prod * alpha;
    }
    float acp = prod;
    float om  = 1.0f - acp;
    sched[t * 8 + 0] = sqrtf(1.0f / acp);
    sched[t * 8 + 1] = sqrtf(1.0f / acp - 1.0f);
    sched[t * 8 + 2] = beta * sqrtf(acp_prev) / om;
    sched[t * 8 + 3] = (1.0f - acp_prev) * sqrtf(alpha) / om;
    float pv = beta * (1.0f - acp_prev) / om;
    sched[t * 8 + 4] = (t > 0) ? sqrtf(pv) : 0.0f;
    uint32_t fk0, fk1;
    threefry2x32(0u, 2u, 0u, (uint32_t)t, fk0, fk1);
    ((uint32_t*)sched)[t * 8 + 5] = fk0;
    ((uint32_t*)sched)[t * 8 + 6] = fk1;
  }
  __syncthreads();
  float acc = bt[d] + bin[d];
  for (int k = 0; k < 64; ++k)
    acc = fmaf(temb[k], Wt[k * 64 + d], acc);
  tpb[t * 64 + d] = acc;
}

// ---------------------------------------------------------------------------
// K_ddpm: 512 blocks x 512 threads (8 waves). Block owns 16 rows.
// Wave w: nt=w&3 (cols 16nt..16nt+15), kc=w>>2 (K-chunk [32kc,32kc+32)).
// Wave kc owns C-rows {quad*4+2kc, quad*4+2kc+1} end-to-end.
#define WLDW  68   // weight row stride (shorts)
#define XLDW  68   // X/H row stride (shorts)
#define PACCW 10   // pacc row stride (floats): float2 per quad

__global__ __launch_bounds__(512, 4)   // honest 4 waves/EU -> 128-VGPR budget
void k_ddpm(const float* __restrict__ Win, const float* __restrict__ Wout,
            const float* __restrict__ bout,
            const float* __restrict__ cproj, const float* __restrict__ tpb,
            const float* __restrict__ sched, float* __restrict__ out)
{
  __shared__ short WiHs[64 * WLDW], WiLs[64 * WLDW];
  __shared__ short WoHs[64 * WLDW], WoLs[64 * WLDW];
  __shared__ short Xh[16 * XLDW], Xl[16 * XLDW], Hh[16 * XLDW], Hl[16 * XLDW];
  __shared__ float pacc[2 * 64 * PACCW];
  // total: 34816 + 8704 + 5120 = 48640 B

  const int tid  = threadIdx.x;
  const int lane = tid & 63;
  const int w    = tid >> 6;
  const int nt   = w & 3;
  const int kc   = w >> 2;
  const int nn   = lane & 15;
  const int quad = lane >> 4;
  const int dim  = nt * 16 + nn;
  const int arow = nn;
  const int r0g  = blockIdx.x * 16;
  const int kofs = kc * 32 + quad * 8;
  const int rA   = quad * 4 + 2 * kc;       // owned C-rows rA, rA+1

  // ---- stage split weights, transposed [n][k]
  for (int idx = tid; idx < 4096; idx += 512) {
    int k = idx >> 6, n = idx & 63;
    short h, l;
    split_bf16(Win[idx], h, l);
    WiHs[n * WLDW + k] = h; WiLs[n * WLDW + k] = l;
    split_bf16(Wout[idx], h, l);
    WoHs[n * WLDW + k] = h; WoLs[n * WLDW + k] = l;
  }

  const float bo = bout[dim];
  const uint32_t jA = (uint32_t)((r0g + rA) * 64 + dim);
  const uint32_t jB = jA + 64u;
  const float cpA = cproj[jA];
  const float cpB = cproj[jB];

  // ---- x_init at owned positions
  float xoA = jax_bits_to_normal(jax_random_bits32(0u, 1u, jA));
  float xoB = jax_bits_to_normal(jax_random_bits32(0u, 1u, jB));
  {
    short h, l;
    split_bf16(xoA, h, l); Xh[rA * XLDW + dim] = h; Xl[rA * XLDW + dim] = l;
    split_bf16(xoB, h, l); Xh[(rA+1) * XLDW + dim] = h; Xl[(rA+1) * XLDW + dim] = l;
  }
  __syncthreads();

  float tp = tpb[199 * 64 + dim];

  // pacc slots: mine (write) and other's (read)
  float* pacc_w = &pacc[(kc * 64 + dim) * PACCW + quad * 2];
  const float* pacc_r = &pacc[((1 - kc) * 64 + dim) * PACCW + quad * 2];

#pragma unroll 1
  for (int t = 199; t >= 0; --t) {
    const float sr   = sched[t * 8 + 0];
    const float srm1 = sched[t * 8 + 1];
    const float c1   = sched[t * 8 + 2];
    const float c2   = sched[t * 8 + 3];
    const float sg   = sched[t * 8 + 4];
    const uint32_t fk0 = ((const uint32_t*)sched)[t * 8 + 5];
    const uint32_t fk1 = ((const uint32_t*)sched)[t * 8 + 6];

    // noise for owned rows (state-independent)
    float nA = jax_bits_to_normal(jax_random_bits32(fk0, fk1, jA));
    float nB = jax_bits_to_normal(jax_random_bits32(fk0, fk1, jB));

    // ---- phase 1: in-GEMV partial over own K-chunk (bias on owned rows)
    f32x4 acc;
    if (kc == 0) { acc[0] = tp + cpA; acc[1] = tp + cpB; acc[2] = 0.f; acc[3] = 0.f; }
    else         { acc[0] = 0.f; acc[1] = 0.f; acc[2] = tp + cpA; acc[3] = tp + cpB; }
    {
      short8 ah = ld_frag(&Xh[arow * XLDW + kofs]);
      short8 al = ld_frag(&Xl[arow * XLDW + kofs]);
      short8 bh = ld_frag(&WiHs[dim * WLDW + kofs]);
      short8 bl = ld_frag(&WiLs[dim * WLDW + kofs]);
      acc = __builtin_amdgcn_mfma_f32_16x16x32_bf16(al, bh, acc, 0, 0, 0);
      acc = __builtin_amdgcn_mfma_f32_16x16x32_bf16(ah, bl, acc, 0, 0, 0);
      acc = __builtin_amdgcn_mfma_f32_16x16x32_bf16(ah, bh, acc, 0, 0, 0);
    }
    // ship only the other wave's row partials
    if (kc == 0) *(float2*)pacc_w = make_float2(acc[2], acc[3]);
    else         *(float2*)pacc_w = make_float2(acc[0], acc[1]);
    __syncthreads();                                    // B1

    // ---- phase 2: finalize h for owned rows, silu, stage H
    {
      float2 o = *(const float2*)pacc_r;
      float vA, vB;
      if (kc == 0) { vA = acc[0] + o.x; vB = acc[1] + o.y; }
      else         { vA = acc[2] + o.x; vB = acc[3] + o.y; }
      vA = vA * __builtin_amdgcn_rcpf(1.0f + __expf(-vA));
      vB = vB * __builtin_amdgcn_rcpf(1.0f + __expf(-vB));
      short h, l;
      split_bf16(vA, h, l); Hh[rA * XLDW + dim] = h; Hl[rA * XLDW + dim] = l;
      split_bf16(vB, h, l); Hh[(rA+1) * XLDW + dim] = h; Hl[(rA+1) * XLDW + dim] = l;
    }
    int tn = (t > 0) ? (t - 1) : 0;
    float tpn = tpb[tn * 64 + dim];                     // prefetch next tp
    __syncthreads();                                    // B2

    // ---- phase 3: out-GEMV partial (bias on owned rows)
    f32x4 eac;
    if (kc == 0) { eac[0] = bo; eac[1] = bo; eac[2] = 0.f; eac[3] = 0.f; }
    else         { eac[0] = 0.f; eac[1] = 0.f; eac[2] = bo; eac[3] = bo; }
    {
      short8 ah = ld_frag(&Hh[arow * XLDW + kofs]);
      short8 al = ld_frag(&Hl[arow * XLDW + kofs]);
      short8 bh = ld_frag(&WoHs[dim * WLDW + kofs]);
      short8 bl = ld_frag(&WoLs[dim * WLDW + kofs]);
      eac = __builtin_amdgcn_mfma_f32_16x16x32_bf16(al, bh, eac, 0, 0, 0);
      eac = __builtin_amdgcn_mfma_f32_16x16x32_bf16(ah, bl, eac, 0, 0, 0);
      eac = __builtin_amdgcn_mfma_f32_16x16x32_bf16(ah, bh, eac, 0, 0, 0);
    }
    if (kc == 0) *(float2*)pacc_w = make_float2(eac[2], eac[3]);
    else         *(float2*)pacc_w = make_float2(eac[0], eac[1]);
    __syncthreads();                                    // B3

    // ---- phase 4: finalize eps for owned rows, update, restage X
    {
      float2 o = *(const float2*)pacc_r;
      float eA, eB;
      if (kc == 0) { eA = eac[0] + o.x; eB = eac[1] + o.y; }
      else         { eA = eac[2] + o.x; eB = eac[3] + o.y; }
      float xcA = fminf(1.f, fmaxf(-1.f, sr * xoA - srm1 * eA));
      float xcB = fminf(1.f, fmaxf(-1.f, sr * xoB - srm1 * eB));
      xoA = c1 * xcA + c2 * xoA + sg * nA;
      xoB = c1 * xcB + c2 * xoB + sg * nB;
      short h, l;
      split_bf16(xoA, h, l); Xh[rA * XLDW + dim] = h; Xl[rA * XLDW + dim] = l;
      split_bf16(xoB, h, l); Xh[(rA+1) * XLDW + dim] = h; Xl[(rA+1) * XLDW + dim] = l;
      tp = tpn;
    }
    __syncthreads();                                    // B4
  }

  out[jA] = xoA;
  out[jB] = xoB;
}

// ---------------------------------------------------------------------------
extern "C" void kernel_launch(void* const* d_in, const int* in_sizes, int n_in,
                              void* d_out, int out_size, void* d_ws, size_t ws_size,
                              hipStream_t stream)
{
  const int*   seq  = (const int*)  d_in[0];
  const float* emb  = (const float*)d_in[1];
  const float* W1   = (const float*)d_in[2];
  const float* b1   = (const float*)d_in[3];
  const float* W2   = (const float*)d_in[4];
  const float* b2   = (const float*)d_in[5];
  const float* Win  = (const float*)d_in[6];
  const float* bin  = (const float*)d_in[7];
  const float* Wt   = (const float*)d_in[8];
  const float* bt   = (const float*)d_in[9];
  const float* Wc   = (const float*)d_in[10];
  const float* bc   = (const float*)d_in[11];
  const float* Wout = (const float*)d_in[12];
  const float* bout = (const float*)d_in[13];

  float* out   = (float*)d_out;
  float* ws    = (float*)d_ws;
  float* cproj = ws;                       // 524288 floats
  float* tpb   = ws + 524288;              // 12800 floats
  float* sched = ws + 524288 + 12800;      // 1600 floats (t*8 layout)
  float* pooled = out;                     // reuse d_out as scratch

  k_pool <<<2048, 256, 0, stream>>>(seq, emb, pooled);
  k_enc  <<<1024, 256, 0, stream>>>(pooled, W1, b1, W2, b2, Wc, bc, cproj);
  k_prep <<<200, 64, 0, stream>>>(Wt, bt, bin, tpb, sched);
  k_ddpm <<<512, 512, 0, stream>>>(Win, Wout, bout, cproj, tpb, sched, out);
}